// Round 3
// baseline (1108.593 us; speedup 1.0000x reference)
//
#include <hip/hip_runtime.h>

#define EPS 1e-9f

constexpr int B_ = 8, N_ = 2048, M_ = 2048;
constexpr int THREADS = 1024;                // 16 waves/block:
constexpr int WAVES = 16;                    //   2 blocks/CU * 16 waves = 32 waves/CU (HW max)
constexpr int RPW = 2;                       // rows per wave
constexpr int RPB = WAVES * RPW;             // 32 rows per block
constexpr int BPB = N_ / RPB;                // 64 blocks per batch
constexpr int GRID = B_ * BPB;               // 512 blocks = 2/CU exactly (no tail)

__global__ __launch_bounds__(256) void init_kernel(float* rL, float* fb,
                                                   float* ss0, float* out) {
    int i = blockIdx.x * blockDim.x + threadIdx.x;
    if (i < B_ * N_) { rL[i] = 1.f; fb[i] = 0.f; ss0[i] = 0.f; }
    if (i < B_) out[i] = 0.f;
}

// One kernel per annealing step s: [phase2 of step s-1] fused with [phase1 of
// step s], sharing a single d2 sweep.
// Round-3 changes (latency-bound diagnosis: 3 configs all ~41us, VALUBusy ~58%,
// occupancy ~6 waves/CU vs 16 cap):
//  - ssp[32] register array + 64KB ssl overlay REPLACED by ds_add_f32 atomics
//    into an 8KB ssacc buffer: -32 VGPR live state, LDS 64.5KB -> 48.1KB.
//  - 1024-thread blocks (16 waves), RPW=2: GRID stays 512 = 2 blocks/CU
//    balanced, but wave residency doubles to 32 waves/CU (8/SIMD) — the HW max.
//  - s=0 specialized p1-only loop (was computing exact zeros through 2 trans ops).
__global__ __launch_bounds__(THREADS, 2) void fused_step(
        const float* __restrict__ xyz1, const float* __restrict__ xyz2,
        float* __restrict__ rLb, float* __restrict__ fb,
        const float* __restrict__ rRp,   // rR(s-1) in   (unused if !has_p2)
        float* __restrict__ rRn_g,       // rR(s)  out   (designated block)
        const float* __restrict__ ssp_g, // ss(s-1) in   (unused if !has_p2)
        float* __restrict__ ssc_g,       // ss(s) atomic accumulate (pre-zeroed)
        float* __restrict__ ssz_g,       // ss(s+1) zeroed here for next kernel
        float* __restrict__ out,
        float l2p, float l2c, int has_p2, int has_p1)
{
    // raw[0:8192)        : sp    = float4 (x,y,z,rn)   32 KB
    // raw[8192:10240)    : sg    = g                    8 KB
    // raw[10240:12288)   : ssacc = ss LDS accumulator   8 KB
    // raw[12288:12304)   : wcost
    __shared__ __align__(16) float raw[6 * M_ + WAVES];
    float4* sp    = (float4*)raw;
    float*  sg    = raw + 4 * M_;
    float*  ssacc = raw + 5 * M_;
    float*  wcost = raw + 6 * M_;

    const int b   = blockIdx.x / BPB;
    const int blk = blockIdx.x % BPB;
    const int n0  = blk * RPB;
    const int tid = threadIdx.x;
    const bool designated = (blk == 0);

    // ---- staging: points + per-column factors for BOTH fused parts ----
    const float* x2 = xyz2 + (size_t)b * M_ * 3;
    for (int m = tid; m < M_; m += THREADS) {
        const float x = x2[3*m], y = x2[3*m+1], z = x2[3*m+2];
        float g = 0.f, rn = 1.f;
        if (has_p2) {
            const float rr = rRp[b * M_ + m];
            const float s  = ssp_g[b * M_ + m];
            const float ratio = fminf(rr / (s + EPS), 1.f);
            g  = rr * ratio;
            rn = fmaxf(rr - s * ratio, 0.f);
        }
        sp[m] = make_float4(x, y, z, rn);
        sg[m] = g;
        ssacc[m] = 0.f;
        if (designated) {
            if (has_p1) rRn_g[b * M_ + m] = rn;
            ssz_g[b * M_ + m] = 0.f;
        }
    }
    __syncthreads();

    const int wave = tid >> 6, lane = tid & 63;
    const int nw = n0 + wave * RPW;

    float xv[RPW], yv[RPW], zv[RPW];
    #pragma unroll
    for (int r = 0; r < RPW; ++r) {
        const float* q = xyz1 + (size_t)(b * N_ + nw + r) * 3;
        xv[r] = q[0]; yv[r] = q[1]; zv[r] = q[2];
    }

    float accd[RPW], accc[RPW], p[RPW];
    #pragma unroll
    for (int r = 0; r < RPW; ++r) { accd[r] = 0.f; accc[r] = 0.f; p[r] = 0.f; }

    // ---- fused sweep: phase2(s-1) cost/rowsum + phase1(s) rowsum ----
    if (has_p1 && has_p2) {
        #pragma unroll
        for (int k = 0; k < 32; ++k) {
            const float4 c = sp[lane + (k << 6)];
            const float  g = sg[lane + (k << 6)];
            #pragma unroll
            for (int r = 0; r < RPW; ++r) {
                const float dx = xv[r]-c.x, dy = yv[r]-c.y, dz = zv[r]-c.z;
                const float d2 = dx*dx + dy*dy + dz*dz;
                const float e = __builtin_amdgcn_exp2f(l2p * d2) * g;
                accd[r] += e;
                accc[r] += e * __builtin_amdgcn_sqrtf(fmaxf(d2, 1e-20f));
                p[r] += __builtin_amdgcn_exp2f(l2c * d2) * c.w;
            }
        }
    } else if (has_p1) {
        // s=0: no phase2 — p-only (accd/accc stay exactly 0, matching g=0 math)
        #pragma unroll
        for (int k = 0; k < 32; ++k) {
            const float4 c = sp[lane + (k << 6)];
            #pragma unroll
            for (int r = 0; r < RPW; ++r) {
                const float dx = xv[r]-c.x, dy = yv[r]-c.y, dz = zv[r]-c.z;
                const float d2 = dx*dx + dy*dy + dz*dz;
                p[r] += __builtin_amdgcn_exp2f(l2c * d2) * c.w;
            }
        }
    } else {
        // s=10: phase2-only
        #pragma unroll
        for (int k = 0; k < 32; ++k) {
            const float4 c = sp[lane + (k << 6)];
            const float  g = sg[lane + (k << 6)];
            #pragma unroll
            for (int r = 0; r < RPW; ++r) {
                const float dx = xv[r]-c.x, dy = yv[r]-c.y, dz = zv[r]-c.z;
                const float d2 = dx*dx + dy*dy + dz*dz;
                const float e = __builtin_amdgcn_exp2f(l2p * d2) * g;
                accd[r] += e;
                accc[r] += e * __builtin_amdgcn_sqrtf(fmaxf(d2, 1e-20f));
            }
        }
    }

    // ---- wave reductions (rows are wave-private) ----
    if (has_p2) {
        #pragma unroll
        for (int r = 0; r < RPW; ++r) {
            #pragma unroll
            for (int off = 32; off >= 1; off >>= 1) {
                accd[r] += __shfl_xor(accd[r], off, 64);
                accc[r] += __shfl_xor(accc[r], off, 64);
            }
        }
    }
    if (has_p1) {
        #pragma unroll
        for (int r = 0; r < RPW; ++r) {
            #pragma unroll
            for (int off = 32; off >= 1; off >>= 1)
                p[r] += __shfl_xor(p[r], off, 64);
        }
    }

    float rl_new[RPW];
    float cw = 0.f;
    if (has_p2) {
        #pragma unroll
        for (int r = 0; r < RPW; ++r) {
            const int idx = b * N_ + nw + r;
            const float fo = fb[idx];               // f(s-1), broadcast load
            const float rl = rLb[idx];
            rl_new[r] = fmaxf(rl - fo * accd[r], 0.f);
            cw += fo * accc[r];
        }
    } else {
        #pragma unroll
        for (int r = 0; r < RPW; ++r) rl_new[r] = 1.f;
    }
    if (lane == 0) wcost[wave] = cw;

    // ---- phase1 colsums: f, ss accumulate via LDS atomics ----
    if (has_p1) {
        float fn[RPW];
        #pragma unroll
        for (int r = 0; r < RPW; ++r)
            fn[r] = rl_new[r] / (p[r] + EPS);
        if (lane == 0) {
            #pragma unroll
            for (int r = 0; r < RPW; ++r) {
                const int idx = b * N_ + nw + r;
                fb[idx]  = fn[r];
                rLb[idx] = rl_new[r];
            }
        }
        // per-lane column partials: recompute e, ds_add_f32 straight into ssacc
        #pragma unroll
        for (int k = 0; k < 32; ++k) {
            const float4 c = sp[lane + (k << 6)];
            float s = 0.f;
            #pragma unroll
            for (int r = 0; r < RPW; ++r) {
                const float dx = xv[r]-c.x, dy = yv[r]-c.y, dz = zv[r]-c.z;
                const float d2 = dx*dx + dy*dy + dz*dz;
                s += __builtin_amdgcn_exp2f(l2c * d2) * fn[r];
            }
            atomicAdd(&ssacc[lane + (k << 6)], s * c.w);
        }
        __syncthreads();   // ssacc complete; wcost visible
        if (tid == 0 && has_p2) {
            float t = 0.f;
            #pragma unroll
            for (int w = 0; w < WAVES; ++w) t += wcost[w];
            atomicAdd(&out[b], t);
        }
        for (int m = tid; m < M_; m += THREADS)
            atomicAdd(&ssc_g[b * M_ + m], ssacc[m]);
    } else {
        __syncthreads();   // wcost visible
        if (tid == 0) {
            float t = 0.f;
            #pragma unroll
            for (int w = 0; w < WAVES; ++w) t += wcost[w];
            atomicAdd(&out[b], t);
        }
    }
}

extern "C" void kernel_launch(void* const* d_in, const int* in_sizes, int n_in,
                              void* d_out, int out_size, void* d_ws, size_t ws_size,
                              hipStream_t stream) {
    const float* xyz1 = (const float*)d_in[0];
    const float* xyz2 = (const float*)d_in[1];
    float* out = (float*)d_out;
    float* ws = (float*)d_ws;
    const int SZ = B_ * N_;          // == B_*M_ == 16384
    float* rL  = ws;
    float* fb  = ws + SZ;
    float* rRb[2] = { ws + 2*SZ, ws + 3*SZ };
    float* ssb[3] = { ws + 4*SZ, ws + 5*SZ, ws + 6*SZ };

    init_kernel<<<(SZ + 255) / 256, 256, 0, stream>>>(rL, fb, ssb[0], out);

    constexpr float LOG2E = 1.4426950408889634f;
    static const float levels[10] = {
        -16384.f, -4096.f, -1024.f, -256.f, -64.f,
        -16.f, -4.f, -1.f, -0.25f, 0.f
    };
    // kernel s (s=0..10): phase2 of step s-1 (if s>0) + phase1 of step s (if s<10)
    for (int s = 0; s <= 10; ++s) {
        const int has_p2 = (s > 0);
        const int has_p1 = (s < 10);
        const float l2p = has_p2 ? levels[s-1] * LOG2E : 0.f;
        const float l2c = has_p1 ? levels[s]   * LOG2E : 0.f;
        fused_step<<<GRID, THREADS, 0, stream>>>(
            xyz1, xyz2, rL, fb,
            rRb[(s + 1) & 1],      // rR(s-1)   (s>=1; unused at s=0)
            rRb[s & 1],            // rR(s) out
            ssb[(s + 2) % 3],      // ss(s-1)   (s>=1; unused at s=0)
            ssb[s % 3],            // ss(s) accumulate (pre-zeroed by kernel s-1 / init)
            ssb[(s + 1) % 3],      // ss(s+1) zeroed for next kernel
            out, l2p, l2c, has_p2, has_p1);
    }
}

// Round 4
// 434.222 us; speedup vs baseline: 2.5531x; 2.5531x over previous
//
#include <hip/hip_runtime.h>

#define EPS 1e-9f

constexpr int B_ = 8, N_ = 2048, M_ = 2048;
constexpr int THREADS = 512;                 // 8 waves/block
constexpr int WAVES = 8;                     // 2 blocks/CU * 8 waves = 16 waves/CU
constexpr int RPW = 4;                       // rows per wave
constexpr int RPB = WAVES * RPW;             // 32 rows per block
constexpr int BPB = N_ / RPB;                // 64 blocks per batch
constexpr int GRID = B_ * BPB;               // 512 blocks = 2/CU exactly

__global__ __launch_bounds__(256) void init_kernel(float* rL, float* fb,
                                                   float* ss0, float* out) {
    int i = blockIdx.x * blockDim.x + threadIdx.x;
    if (i < B_ * N_) { rL[i] = 1.f; fb[i] = 0.f; ss0[i] = 0.f; }
    if (i < B_) out[i] = 0.f;
}

// One kernel per annealing step s: [phase2 of step s-1] fused with [phase1 of
// step s], sharing a single d2 sweep. Round-2 skeleton (ssl overlay + reg
// buffering; LDS atomics of round-3 REVERTED: 16-way same-address ds_add
// contention serialized the colsum, 41->109us).
// Round-4 changes:
//  - e^4 trick: levels descend by exactly 4x, so for s=1..8
//    exp2(l2p*d2) == exp2(l2c*d2)^4 — replaces one exp2 (trans pipe) with two
//    squarings (VALU). Main-sweep trans ops 3 -> 2.
//  - s=0 specialized p-only loop (was computing exact zeros via 2 trans/pair).
__global__ __launch_bounds__(THREADS, 2) void fused_step(
        const float* __restrict__ xyz1, const float* __restrict__ xyz2,
        float* __restrict__ rLb, float* __restrict__ fb,
        const float* __restrict__ rRp,   // rR(s-1) in   (unused if !has_p2)
        float* __restrict__ rRn_g,       // rR(s)  out   (designated block)
        const float* __restrict__ ssp_g, // ss(s-1) in   (unused if !has_p2)
        float* __restrict__ ssc_g,       // ss(s) atomic accumulate (pre-zeroed)
        float* __restrict__ ssz_g,       // ss(s+1) zeroed here for next kernel
        float* __restrict__ out,
        float l2p, float l2c, int has_p2, int has_p1, int pow4)
{
    // raw[0:8192)        : sp  = float4 (x,y,z,rn)      32 KB
    // raw[8192:10240)    : sg  = g                       8 KB
    // raw[0:16384)       : ssl overlay (8 waves x 2048) 64 KB, after passB sync
    // raw[16384:16392)   : wcost
    __shared__ __align__(16) float raw[8 * M_ + WAVES];
    float4* sp    = (float4*)raw;
    float*  sg    = raw + 4 * M_;
    float*  ssl   = raw;
    float*  wcost = raw + 8 * M_;

    const int b   = blockIdx.x / BPB;
    const int blk = blockIdx.x % BPB;
    const int n0  = blk * RPB;
    const int tid = threadIdx.x;
    const bool designated = (blk == 0);

    // ---- staging: points + per-column factors for BOTH fused parts ----
    const float* x2 = xyz2 + (size_t)b * M_ * 3;
    for (int m = tid; m < M_; m += THREADS) {
        const float x = x2[3*m], y = x2[3*m+1], z = x2[3*m+2];
        float g = 0.f, rn = 1.f;
        if (has_p2) {
            const float rr = rRp[b * M_ + m];
            const float s  = ssp_g[b * M_ + m];
            const float ratio = fminf(rr / (s + EPS), 1.f);
            g  = rr * ratio;
            rn = fmaxf(rr - s * ratio, 0.f);
        }
        sp[m] = make_float4(x, y, z, rn);
        sg[m] = g;
        if (designated) {
            if (has_p1) rRn_g[b * M_ + m] = rn;
            ssz_g[b * M_ + m] = 0.f;
        }
    }
    __syncthreads();

    const int wave = tid >> 6, lane = tid & 63;
    const int nw = n0 + wave * RPW;

    float xv[RPW], yv[RPW], zv[RPW];
    #pragma unroll
    for (int r = 0; r < RPW; ++r) {
        const float* q = xyz1 + (size_t)(b * N_ + nw + r) * 3;
        xv[r] = q[0]; yv[r] = q[1]; zv[r] = q[2];
    }

    float accd[RPW], accc[RPW], p[RPW];
    #pragma unroll
    for (int r = 0; r < RPW; ++r) { accd[r] = 0.f; accc[r] = 0.f; p[r] = 0.f; }

    // ---- fused sweep: phase2(s-1) cost/rowsum + phase1(s) rowsum ----
    if (has_p2 && has_p1 && pow4) {
        // s=1..8: exp2(l2p*d2) == exp2(l2c*d2)^4 exactly (levels ratio 4)
        #pragma unroll
        for (int k = 0; k < 32; ++k) {
            const float4 c = sp[lane + (k << 6)];
            const float  g = sg[lane + (k << 6)];
            #pragma unroll
            for (int r = 0; r < RPW; ++r) {
                const float dx = xv[r]-c.x, dy = yv[r]-c.y, dz = zv[r]-c.z;
                const float d2 = dx*dx + dy*dy + dz*dz;
                const float ec = __builtin_amdgcn_exp2f(l2c * d2);
                const float e2 = ec * ec;
                const float e  = (e2 * e2) * g;
                accd[r] += e;
                accc[r] += e * __builtin_amdgcn_sqrtf(fmaxf(d2, 1e-20f));
                p[r] += ec * c.w;
            }
        }
    } else if (has_p2 && has_p1) {
        // s=9 (l2c == 0): dual-exp2 path
        #pragma unroll
        for (int k = 0; k < 32; ++k) {
            const float4 c = sp[lane + (k << 6)];
            const float  g = sg[lane + (k << 6)];
            #pragma unroll
            for (int r = 0; r < RPW; ++r) {
                const float dx = xv[r]-c.x, dy = yv[r]-c.y, dz = zv[r]-c.z;
                const float d2 = dx*dx + dy*dy + dz*dz;
                const float e = __builtin_amdgcn_exp2f(l2p * d2) * g;
                accd[r] += e;
                accc[r] += e * __builtin_amdgcn_sqrtf(fmaxf(d2, 1e-20f));
                p[r] += __builtin_amdgcn_exp2f(l2c * d2) * c.w;
            }
        }
    } else if (has_p1) {
        // s=0: no phase2 — p-only (accd/accc stay exactly 0, matching g=0 math)
        #pragma unroll
        for (int k = 0; k < 32; ++k) {
            const float4 c = sp[lane + (k << 6)];
            #pragma unroll
            for (int r = 0; r < RPW; ++r) {
                const float dx = xv[r]-c.x, dy = yv[r]-c.y, dz = zv[r]-c.z;
                const float d2 = dx*dx + dy*dy + dz*dz;
                p[r] += __builtin_amdgcn_exp2f(l2c * d2) * c.w;
            }
        }
    } else {
        // s=10: phase2-only
        #pragma unroll
        for (int k = 0; k < 32; ++k) {
            const float4 c = sp[lane + (k << 6)];
            const float  g = sg[lane + (k << 6)];
            #pragma unroll
            for (int r = 0; r < RPW; ++r) {
                const float dx = xv[r]-c.x, dy = yv[r]-c.y, dz = zv[r]-c.z;
                const float d2 = dx*dx + dy*dy + dz*dz;
                const float e = __builtin_amdgcn_exp2f(l2p * d2) * g;
                accd[r] += e;
                accc[r] += e * __builtin_amdgcn_sqrtf(fmaxf(d2, 1e-20f));
            }
        }
    }

    // ---- wave reductions (rows are wave-private) ----
    if (has_p2) {
        #pragma unroll
        for (int r = 0; r < RPW; ++r) {
            #pragma unroll
            for (int off = 32; off >= 1; off >>= 1) {
                accd[r] += __shfl_xor(accd[r], off, 64);
                accc[r] += __shfl_xor(accc[r], off, 64);
            }
        }
    }
    if (has_p1) {
        #pragma unroll
        for (int r = 0; r < RPW; ++r) {
            #pragma unroll
            for (int off = 32; off >= 1; off >>= 1)
                p[r] += __shfl_xor(p[r], off, 64);
        }
    }

    float rl_new[RPW];
    float cw = 0.f;
    if (has_p2) {
        #pragma unroll
        for (int r = 0; r < RPW; ++r) {
            const int idx = b * N_ + nw + r;
            const float fo = fb[idx];               // f(s-1), broadcast load
            const float rl = rLb[idx];
            rl_new[r] = fmaxf(rl - fo * accd[r], 0.f);
            cw += fo * accc[r];
        }
    } else {
        #pragma unroll
        for (int r = 0; r < RPW; ++r) rl_new[r] = 1.f;
    }
    if (lane == 0) wcost[wave] = cw;
    __syncthreads();
    if (tid == 0 && has_p2) {
        float t = 0.f;
        #pragma unroll
        for (int w = 0; w < WAVES; ++w) t += wcost[w];
        atomicAdd(&out[b], t);
    }

    // ---- phase1 colsums: f, ss accumulate ----
    if (has_p1) {
        float fn[RPW];
        #pragma unroll
        for (int r = 0; r < RPW; ++r)
            fn[r] = rl_new[r] / (p[r] + EPS);
        if (lane == 0) {
            #pragma unroll
            for (int r = 0; r < RPW; ++r) {
                const int idx = b * N_ + nw + r;
                fb[idx]  = fn[r];
                rLb[idx] = rl_new[r];
            }
        }
        // per-lane column partials (recompute e; no per-element storage)
        float ssp[32];
        #pragma unroll
        for (int k = 0; k < 32; ++k) {
            const float4 c = sp[lane + (k << 6)];
            float s = 0.f;
            #pragma unroll
            for (int r = 0; r < RPW; ++r) {
                const float dx = xv[r]-c.x, dy = yv[r]-c.y, dz = zv[r]-c.z;
                const float d2 = dx*dx + dy*dy + dz*dz;
                s += __builtin_amdgcn_exp2f(l2c * d2) * fn[r];
            }
            ssp[k] = s * c.w;
        }
        __syncthreads();   // all sp/sg reads done -> ssl overlay safe
        #pragma unroll
        for (int k = 0; k < 32; ++k)
            ssl[wave * M_ + lane + (k << 6)] = ssp[k];
        __syncthreads();
        for (int m = tid; m < M_; m += THREADS) {
            float s = ssl[m]          + ssl[M_ + m]     + ssl[2*M_ + m]
                    + ssl[3*M_ + m]   + ssl[4*M_ + m]   + ssl[5*M_ + m]
                    + ssl[6*M_ + m]   + ssl[7*M_ + m];
            atomicAdd(&ssc_g[b * M_ + m], s);
        }
    }
}

extern "C" void kernel_launch(void* const* d_in, const int* in_sizes, int n_in,
                              void* d_out, int out_size, void* d_ws, size_t ws_size,
                              hipStream_t stream) {
    const float* xyz1 = (const float*)d_in[0];
    const float* xyz2 = (const float*)d_in[1];
    float* out = (float*)d_out;
    float* ws = (float*)d_ws;
    const int SZ = B_ * N_;          // == B_*M_ == 16384
    float* rL  = ws;
    float* fb  = ws + SZ;
    float* rRb[2] = { ws + 2*SZ, ws + 3*SZ };
    float* ssb[3] = { ws + 4*SZ, ws + 5*SZ, ws + 6*SZ };

    init_kernel<<<(SZ + 255) / 256, 256, 0, stream>>>(rL, fb, ssb[0], out);

    constexpr float LOG2E = 1.4426950408889634f;
    static const float levels[10] = {
        -16384.f, -4096.f, -1024.f, -256.f, -64.f,
        -16.f, -4.f, -1.f, -0.25f, 0.f
    };
    // kernel s (s=0..10): phase2 of step s-1 (if s>0) + phase1 of step s (if s<10)
    for (int s = 0; s <= 10; ++s) {
        const int has_p2 = (s > 0);
        const int has_p1 = (s < 10);
        const float l2p = has_p2 ? levels[s-1] * LOG2E : 0.f;
        const float l2c = has_p1 ? levels[s]   * LOG2E : 0.f;
        // levels descend by exactly 4x -> l2p == 4*l2c bit-exactly (exponent
        // shift), except s=9 where l2c == 0.
        const int pow4 = (has_p2 && has_p1 && l2c != 0.f && l2p == 4.f * l2c);
        fused_step<<<GRID, THREADS, 0, stream>>>(
            xyz1, xyz2, rL, fb,
            rRb[(s + 1) & 1],      // rR(s-1)   (s>=1; unused at s=0)
            rRb[s & 1],            // rR(s) out
            ssb[(s + 2) % 3],      // ss(s-1)   (s>=1; unused at s=0)
            ssb[s % 3],            // ss(s) accumulate (pre-zeroed by kernel s-1 / init)
            ssb[(s + 1) % 3],      // ss(s+1) zeroed for next kernel
            out, l2p, l2c, has_p2, has_p1, pow4);
    }
}